// Round 11
// baseline (200.053 us; speedup 1.0000x reference)
//
#include <hip/hip_runtime.h>
#include <math.h>

// Problem constants
#define NBT 512
#define NF  256
#define NC  768
#define NROW 64
#define NORG 16
#define NE  128
#define SLD 260      // fp32 LDS row stride (16-row tiles)
#define SY  264      // bf16 LDS row stride for y

// ---- ws byte offsets ----
#define WS_SW_LAB1 0         // 256x256 bf16, 32-style frag order
#define WS_SW_ABN1 131072
#define WS_SW_ORG  1441792   // 256x256, 16-style
#define WS_SW_O2A  1572864
#define WS_SUMREL  1703936   // 16x768 f32 per-organ sums of lab_rel
#define WS_LAB_CB  1753088   // 128x256 f32 (bias folded)
#define WS_ABN_CB  1884160
#define WS_BORG    2015232   // 16x256 f32 borg bias matrix (full path)
#define WS_ADDSUM  2015232   // alias: raw sumRel@D for fallback path
#define WS_WCNT    2031616   // 64x16 f32
#define WS_INVL    2035712
#define WS_INVA    2035776
#define WS_MASK    2035840
#define WS_SRTL    2035904   // 128 ints: (row<<24)|(org<<16)|e, organ-sorted ASC
#define WS_SRTA    2036544
#define WS_DW      2097152   // 768x256 f32 = D @ W_org (full path)
#define WS_NEED    2883584

typedef __attribute__((ext_vector_type(8)))  short bf16x8;
typedef __attribute__((ext_vector_type(16))) float f32x16;
typedef __attribute__((ext_vector_type(4)))  float f32x4;

__device__ __forceinline__ short f2bf(float f) {
    union { float f; unsigned u; } v; v.f = f;
    unsigned r = v.u + 0x7FFF + ((v.u >> 16) & 1);   // RNE
    return (short)(r >> 16);
}
__device__ __forceinline__ float bf2f(short s) {
    return __uint_as_float(((unsigned)(unsigned short)s) << 16);
}
__device__ __forceinline__ float tanh_fast(float x) {
    float xc = fminf(fmaxf(x, -15.f), 15.f);
    float e = __expf(2.f * xc);
    return 1.f - 2.f * __builtin_amdgcn_rcpf(e + 1.f);
}
__device__ __forceinline__ f32x16 mfma32(bf16x8 a, bf16x8 b, f32x16 c) {
    return __builtin_amdgcn_mfma_f32_32x32x16_bf16(a, b, c, 0, 0, 0);
}
__device__ __forceinline__ f32x4 mfma16(bf16x8 a, bf16x8 b, f32x4 c) {
    return __builtin_amdgcn_mfma_f32_16x16x32_bf16(a, b, c, 0, 0, 0);
}
__device__ __forceinline__ bf16x8 pack_f4(float4 x0, float4 x1) {
    union { bf16x8 v; unsigned u[4]; } r;
    r.u[0] = __builtin_amdgcn_perm(__float_as_uint(x0.y), __float_as_uint(x0.x), 0x07060302);
    r.u[1] = __builtin_amdgcn_perm(__float_as_uint(x0.w), __float_as_uint(x0.z), 0x07060302);
    r.u[2] = __builtin_amdgcn_perm(__float_as_uint(x1.y), __float_as_uint(x1.x), 0x07060302);
    r.u[3] = __builtin_amdgcn_perm(__float_as_uint(x1.w), __float_as_uint(x1.z), 0x07060302);
    return r.v;
}
__device__ __forceinline__ bf16x8 pack_a16(const float* __restrict__ p) {
    float4 x0 = *(const float4*)p;
    float4 x1 = *(const float4*)(p + 4);
    return pack_f4(x0, x1);
}

// ---------------------------------------------------------------------------
// pk_pre2: 433 blocks (full path) / 241 (fallback):
//   0..63    cb tables (B read on-the-fly from global W)
//   64..111  sumRel (48 parallel blocks -> WS_SUMREL)
//   112      metadata (counts, sorted edge lists, wcnt)
//   113..240 weight swizzles (LAB1, ABN1, ORG, O2A)
//   241..432 DW = D @ W_org (192 tiny blocks; independent of sumRel)
// ---------------------------------------------------------------------------
__device__ __forceinline__ void swz32(const float* __restrict__ src, short* __restrict__ dst, int s) {
    const int l = s & 63, rest = s >> 6;
    const int nt = rest & 7, k16 = rest >> 3;
    const int n = nt * 32 + (l & 31);
    const int kb = k16 * 16 + ((l >> 5) & 1) * 8;
    bf16x8 v;
    #pragma unroll
    for (int j = 0; j < 8; ++j) v[j] = f2bf(src[(kb + j) * NF + n]);
    *(bf16x8*)(dst + s * 8) = v;
}
__device__ __forceinline__ void swz16(const float* __restrict__ src, short* __restrict__ dst, int s) {
    const int l = s & 63, rest = s >> 6;
    const int nt = rest & 15, k32 = rest >> 4;
    const int n = nt * 16 + (l & 15);
    const int kb = k32 * 32 + ((l >> 4) & 3) * 8;
    bf16x8 v;
    #pragma unroll
    for (int j = 0; j < 8; ++j) v[j] = f2bf(src[(kb + j) * NF + n]);
    *(bf16x8*)(dst + s * 8) = v;
}

__global__ __launch_bounds__(256) void pk_pre2(
    const float* __restrict__ W_lab, const float* __restrict__ W_abn,
    const float* __restrict__ W_org,
    const float* __restrict__ W_o2a, const float* __restrict__ D,
    const float* __restrict__ lab_rel,
    const float* __restrict__ lab_con, const float* __restrict__ abn_con,
    const float* __restrict__ abn_rel,
    const float* __restrict__ b_lab, const float* __restrict__ b_abn,
    const int* __restrict__ lab_idx, const int* __restrict__ lab_org_idx,
    const int* __restrict__ abn_idx, const int* __restrict__ abn_org_idx,
    const int* __restrict__ o2a_abn_idx, const int* __restrict__ o2a_org_idx,
    char* __restrict__ ws) {
    __shared__ __align__(16) float sP[4 * 1024];     // 16 KB cross-wave reduce
    const int bid = blockIdx.x;
    const int tid = threadIdx.x;
    if (bid < 64) {
        // ---- cb tables: (con[idx]+rel) @ W2 + bias.  B read on-the-fly. ----
        const int l = tid & 63, w = tid >> 6;
        const int side = bid >> 5;                   // 0 lab, 1 abn
        const int b2 = bid & 31;
        const int mq = b2 >> 3, nb = b2 & 7;         // 4 m-tiles x 8 n-tiles
        const int em = mq * 32;
        const float* W2  = side ? (W_abn + NF * NF) : (W_lab + NF * NF);
        const float* con = side ? abn_con : lab_con;
        const float* rel = side ? abn_rel : lab_rel;
        const int*   idx = side ? abn_idx : lab_idx;

        f32x16 acc;
        #pragma unroll
        for (int r = 0; r < 16; ++r) acc[r] = 0.f;

        const int e  = em + (l & 31);
        const int kk = ((l >> 5) & 1) * 8;
        const int n  = nb * 32 + (l & 31);
        const float* cp = con + idx[e] * NC;
        const float* rp = rel + e * NC;
        #pragma unroll 4
        for (int k16 = 0; k16 < 12; ++k16) {
            const int k = (w * 12 + k16) * 16 + kk;
            float4 c0 = *(const float4*)(cp + k);
            float4 c1 = *(const float4*)(cp + k + 4);
            float4 r0 = *(const float4*)(rp + k);
            float4 r1 = *(const float4*)(rp + k + 4);
            float v[8] = {c0.x + r0.x, c0.y + r0.y, c0.z + r0.z, c0.w + r0.w,
                          c1.x + r1.x, c1.y + r1.y, c1.z + r1.z, c1.w + r1.w};
            bf16x8 af;
            #pragma unroll
            for (int j = 0; j < 8; ++j) af[j] = f2bf(v[j]);
            const float* wp = W2 + k * NF + n;       // B col n, rows k..k+7
            bf16x8 bv;
            #pragma unroll
            for (int j = 0; j < 8; ++j) bv[j] = f2bf(wp[j * NF]);
            acc = mfma32(af, bv, acc);
        }
        #pragma unroll
        for (int r = 0; r < 16; ++r) sP[w * 1024 + r * 64 + l] = acc[r];
        __syncthreads();
        float* outp = (float*)(ws + (side ? WS_ABN_CB : WS_LAB_CB));
        const float* bias = side ? b_abn : b_lab;
        #pragma unroll
        for (int q = 0; q < 4; ++q) {
            const int idx2 = q * 256 + tid;
            float v = sP[idx2] + sP[1024 + idx2] + sP[2048 + idx2] + sP[3072 + idx2];
            const int reg = idx2 >> 6, ll = idx2 & 63;
            const int er = (reg & 3) + 8 * (reg >> 2) + 4 * (ll >> 5);
            const int col = nb * 32 + (ll & 31);
            outp[(em + er) * NF + col] = v + bias[col];
        }
    } else if (bid < 112) {
        // ---- sumRel[o][k] = sum over lab edges with org==o of lab_rel[e][k] ----
        const int b2 = bid - 64;
        const int o = b2 / 3, kth = b2 % 3;
        const int k = kth * 256 + tid;
        float s = 0.f;
        #pragma unroll 16
        for (int e = 0; e < NE; ++e) {
            const float v = lab_rel[e * NC + k];
            s += (lab_org_idx[e] == o) ? v : 0.f;
        }
        ((float*)(ws + WS_SUMREL))[o * NC + k] = s;
    } else if (bid == 112) {
        // ---- metadata: counts, organ-sorted edge lists, wcnt ----
        __shared__ int cL[NORG], cA[NORG], cC[NROW * NORG];
        __shared__ int goL[NORG + 1], goA[NORG + 1], curL[NORG], curA[NORG];
        const int t = tid;
        for (int i = t; i < NROW * NORG; i += 256) cC[i] = 0;
        if (t < NORG) { cL[t] = 0; cA[t] = 0; }
        __syncthreads();
        if (t < NE) {
            atomicAdd(&cL[lab_org_idx[t]], 1);
            atomicAdd(&cA[abn_org_idx[t]], 1);
            atomicAdd(&cC[o2a_abn_idx[t] * NORG + o2a_org_idx[t]], 1);
        }
        __syncthreads();
        if (t == 0) { int s = 0; for (int o = 0; o < NORG; ++o) { goL[o] = s; s += cL[o]; } goL[NORG] = s; }
        if (t == 1) { int s = 0; for (int o = 0; o < NORG; ++o) { goA[o] = s; s += cA[o]; } goA[NORG] = s; }
        __syncthreads();
        if (t < NORG) { curL[t] = goL[t]; curA[t] = goA[t]; }
        __syncthreads();
        if (t < NE) {
            const int ol = lab_org_idx[t], oa = abn_org_idx[t];
            int p = atomicAdd(&curL[ol], 1);
            ((int*)(ws + WS_SRTL))[p] = (lab_idx[t] << 24) | (ol << 16) | t;
            int q = atomicAdd(&curA[oa], 1);
            ((int*)(ws + WS_SRTA))[q] = (abn_idx[t] << 24) | (oa << 16) | t;
        }
        if (t < NORG) {
            ((float*)(ws + WS_INVL))[t] = cL[t] ? 1.f / (float)cL[t] : 0.f;
            ((float*)(ws + WS_INVA))[t] = cA[t] ? 1.f / (float)cA[t] : 0.f;
            ((float*)(ws + WS_MASK))[t] = (cL[t] || cA[t]) ? 1.f : 0.f;
        }
        if (t < NROW) {
            int dega = 0;
            for (int o = 0; o < NORG; ++o) dega += cC[t * NORG + o];
            float inv = 1.f / (float)(dega > 1 ? dega : 1);
            for (int o = 0; o < NORG; ++o)
                ((float*)(ws + WS_WCNT))[t * NORG + o] = (float)cC[t * NORG + o] * inv;
        }
    } else if (bid < 241) {
        const int gid = (bid - 113) * 256 + tid;
        if      (gid <  8192) swz32(W_lab, (short*)(ws + WS_SW_LAB1), gid);
        else if (gid < 16384) swz32(W_abn, (short*)(ws + WS_SW_ABN1), gid - 8192);
        else if (gid < 24576) swz16(W_org, (short*)(ws + WS_SW_ORG),  gid - 16384);
        else                  swz16(W_o2a, (short*)(ws + WS_SW_O2A),  gid - 24576);
    } else {
        // ---- DW = D @ W_org  (768x256 @ 256x256), 192 blocks of 32x32 ----
        const int b = bid - 241;
        const int mq = b >> 3, nb = b & 7;           // 24 m-tiles x 8 n-tiles
        const int l = tid & 63, w = tid >> 6;
        f32x16 acc;
        #pragma unroll
        for (int r = 0; r < 16; ++r) acc[r] = 0.f;
        const int row = mq * 32 + (l & 31);
        const int kk = ((l >> 5) & 1) * 8;
        const int n = nb * 32 + (l & 31);
        #pragma unroll
        for (int k16 = 0; k16 < 4; ++k16) {
            const int k = w * 64 + k16 * 16 + kk;
            bf16x8 af = pack_a16(D + row * NF + k);
            const float* wp = W_org + k * NF + n;
            bf16x8 bv;
            #pragma unroll
            for (int j = 0; j < 8; ++j) bv[j] = f2bf(wp[j * NF]);
            acc = mfma32(af, bv, acc);
        }
        #pragma unroll
        for (int r = 0; r < 16; ++r) sP[w * 1024 + r * 64 + l] = acc[r];
        __syncthreads();
        float* outp = (float*)(ws + WS_DW);
        #pragma unroll
        for (int q = 0; q < 4; ++q) {
            const int idx2 = q * 256 + tid;
            float v = sP[idx2] + sP[1024 + idx2] + sP[2048 + idx2] + sP[3072 + idx2];
            const int reg = idx2 >> 6, ll = idx2 & 63;
            const int er = (reg & 3) + 8 * (reg >> 2) + 4 * (ll >> 5);
            const int col = nb * 32 + (ll & 31);
            outp[(mq * 32 + er) * NF + col] = v;
        }
    }
}

// ---------------------------------------------------------------------------
// pk_mid: 8 blocks. borg = (invL-rowscaled sumRel) @ DW + b_org -> WS_BORG.
// ---------------------------------------------------------------------------
__global__ __launch_bounds__(256) void pk_mid(
    const float* __restrict__ b_org, char* __restrict__ ws) {
    __shared__ __align__(16) float sP[4 * 1024];
    const int tid = threadIdx.x;
    const int nb = blockIdx.x;
    const int l = tid & 63, w = tid >> 6;
    const float* sr = (const float*)(ws + WS_SUMREL);
    const float* dw = (const float*)(ws + WS_DW);
    const float* invL = (const float*)(ws + WS_INVL);
    f32x16 acc;
    #pragma unroll
    for (int r = 0; r < 16; ++r) acc[r] = 0.f;
    const int row = l & 31;
    const int kk = ((l >> 5) & 1) * 8;
    const int n = nb * 32 + (l & 31);
    const float il = (row < NORG) ? invL[row] : 0.f;
    const float* cp = sr + row * NC;
    #pragma unroll 4
    for (int k16 = 0; k16 < 12; ++k16) {
        const int k = w * 192 + k16 * 16 + kk;
        bf16x8 af;
        if (row < NORG) {
            float4 x0 = *(const float4*)(cp + k);
            float4 x1 = *(const float4*)(cp + k + 4);
            af[0] = f2bf(x0.x * il); af[1] = f2bf(x0.y * il);
            af[2] = f2bf(x0.z * il); af[3] = f2bf(x0.w * il);
            af[4] = f2bf(x1.x * il); af[5] = f2bf(x1.y * il);
            af[6] = f2bf(x1.z * il); af[7] = f2bf(x1.w * il);
        } else {
            #pragma unroll
            for (int j = 0; j < 8; ++j) af[j] = 0;
        }
        const float* dp = dw + k * NF + n;
        bf16x8 bv;
        #pragma unroll
        for (int j = 0; j < 8; ++j) bv[j] = f2bf(dp[j * NF]);
        acc = mfma32(af, bv, acc);
    }
    #pragma unroll
    for (int r = 0; r < 16; ++r) sP[w * 1024 + r * 64 + l] = acc[r];
    __syncthreads();
    float* outp = (float*)(ws + WS_BORG);
    #pragma unroll
    for (int q = 0; q < 4; ++q) {
        const int idx2 = q * 256 + tid;
        float v = sP[idx2] + sP[1024 + idx2] + sP[2048 + idx2] + sP[3072 + idx2];
        const int reg = idx2 >> 6, ll = idx2 & 63;
        const int er = (reg & 3) + 8 * (reg >> 2) + 4 * (ll >> 5);
        const int col = nb * 32 + (ll & 31);
        if (er < NORG) outp[er * NF + col] = v + b_org[col];
    }
}

// ---------------------------------------------------------------------------
// gemm_small8 variants: 512-thread (8-wave). Each wave owns 2 n-tiles of 16.
// ---------------------------------------------------------------------------
__device__ __forceinline__ void gemm_small8_borg(
    const float* __restrict__ sIn, const short* __restrict__ Bsw,
    const float* __restrict__ borg, const float* __restrict__ mask,
    float* __restrict__ sOut, int tid) {
    const int l = tid & 63, w = tid >> 6;            // w 0..7
    f32x4 acc[2];
    #pragma unroll
    for (int i = 0; i < 2; ++i) { acc[i][0] = 0.f; acc[i][1] = 0.f; acc[i][2] = 0.f; acc[i][3] = 0.f; }
    #pragma unroll 2
    for (int k32 = 0; k32 < 8; ++k32) {
        const float* ap = sIn + (l & 15) * SLD + k32 * 32 + ((l >> 4) & 3) * 8;
        bf16x8 af = pack_a16(ap);
        #pragma unroll
        for (int nt = 0; nt < 2; ++nt) {
            bf16x8 bfv = *(const bf16x8*)(Bsw + ((k32 * 16 + w * 2 + nt) * 64 + l) * 8);
            acc[nt] = mfma16(af, bfv, acc[nt]);
        }
    }
    #pragma unroll
    for (int nt = 0; nt < 2; ++nt) {
        const int col = (w * 2 + nt) * 16 + (l & 15);
        #pragma unroll
        for (int reg = 0; reg < 4; ++reg) {
            const int row = ((l >> 4) & 3) * 4 + reg;
            float v = acc[nt][reg] + borg[row * NF + col];
            sOut[row * SLD + col] = tanh_fast(v) * mask[row];
        }
    }
}
__device__ __forceinline__ void gemm_small8_vec(
    const float* __restrict__ sIn, const short* __restrict__ Bsw,
    const float* __restrict__ bias, float* __restrict__ sOut, int tid) {
    const int l = tid & 63, w = tid >> 6;
    f32x4 acc[2];
    #pragma unroll
    for (int i = 0; i < 2; ++i) { acc[i][0] = 0.f; acc[i][1] = 0.f; acc[i][2] = 0.f; acc[i][3] = 0.f; }
    #pragma unroll 2
    for (int k32 = 0; k32 < 8; ++k32) {
        const float* ap = sIn + (l & 15) * SLD + k32 * 32 + ((l >> 4) & 3) * 8;
        bf16x8 af = pack_a16(ap);
        #pragma unroll
        for (int nt = 0; nt < 2; ++nt) {
            bf16x8 bfv = *(const bf16x8*)(Bsw + ((k32 * 16 + w * 2 + nt) * 64 + l) * 8);
            acc[nt] = mfma16(af, bfv, acc[nt]);
        }
    }
    #pragma unroll
    for (int nt = 0; nt < 2; ++nt) {
        const int col = (w * 2 + nt) * 16 + (l & 15);
        const float b = bias[col];
        #pragma unroll
        for (int reg = 0; reg < 4; ++reg) {
            const int row = ((l >> 4) & 3) * 4 + reg;
            sOut[row * SLD + col] = acc[nt][reg] + b;
        }
    }
}

// ---------------------------------------------------------------------------
// kg_fuse2: ONE block per bt (512 blocks x 512 threads). Lab then abn pass
// accumulate organ means into LDS (inv folded at flush; addR folded into the
// borg bias matrix); backend runs in the same block.
// T14 async-STAGE: abn A-tile global loads are issued into registers right
// after the lab Y-writeback; they fly under the entire lab edge loop and are
// drained into LDS only at the side-1 loop-top barrier.
// ---------------------------------------------------------------------------
__global__ __launch_bounds__(512, 2) void kg_fuse2(
    const float* __restrict__ lab_feats, const float* __restrict__ abn_feats,
    const float* __restrict__ b_o2a,
    const char* __restrict__ ws, float* __restrict__ out) {
    __shared__ __align__(16) short sY[NROW * SY];    // 33792 B: A-stage / Y / backend
    __shared__ __align__(16) float sAcc[NORG * SLD]; // 16640 B organ means
    __shared__ float sWc[NROW * NORG];               // 4096 B
    __shared__ int sEL[NE], sEA[NE];
    __shared__ float sOv[2 * NF];                    // boundary-organ partials
    __shared__ float sInvL[NORG], sInvA[NORG], sMsk[NORG];

    const int tid = threadIdx.x;
    const int bt = blockIdx.x;

    if (tid < NE)          sEL[tid]      = ((const int*)(ws + WS_SRTL))[tid];
    else if (tid < 2 * NE) sEA[tid - NE] = ((const int*)(ws + WS_SRTA))[tid - NE];
    else {
        const int u = tid - 2 * NE;
        if      (u < 16) sInvL[u]       = ((const float*)(ws + WS_INVL))[u];
        else if (u < 32) sInvA[u - 16]  = ((const float*)(ws + WS_INVA))[u - 16];
        else if (u < 48) sMsk[u - 32]   = ((const float*)(ws + WS_MASK))[u - 32];
    }
    #pragma unroll
    for (int i = tid; i < NROW * NORG; i += 512)
        sWc[i] = ((const float*)(ws + WS_WCNT))[i];
    // zero-init organ means (cols 0..255)
    #pragma unroll
    for (int i = tid; i < NORG * NF; i += 512)
        sAcc[(i >> 8) * SLD + (i & 255)] = 0.f;

    const int l = tid & 63, w = tid >> 6;
    float4 pfa[4], pfb[4];                           // abn A-tile prefetch regs

    for (int side = 0; side < 2; ++side) {
        const float* X   = (side ? abn_feats : lab_feats) + bt * (NROW * NF);
        const short* Bsw = (const short*)(ws + (side ? WS_SW_ABN1 : WS_SW_LAB1));
        const float* cb  = (const float*)(ws + (side ? WS_ABN_CB : WS_LAB_CB));
        const int* sE    = side ? sEA : sEL;
        const float* sInv = side ? sInvA : sInvL;

        __syncthreads();             // prior uses of sY / sAcc ordering
        // ---- stage full A tile (2048 lane-frags) ----
        if (side == 0) {
            #pragma unroll
            for (int ss = 0; ss < 4; ++ss) {
                const int s = tid + 512 * ss;
                const int k16 = s >> 7, rt = (s >> 6) & 1, ll = s & 63;
                const int row = rt * 32 + (ll & 31);
                const int kb = k16 * 16 + ((ll >> 5) & 1) * 8;
                *(bf16x8*)(sY + s * 8) = pack_a16(X + row * NF + kb);
            }
        } else {
            // drain the prefetched abn tile (vmcnt waits land here)
            #pragma unroll
            for (int ss = 0; ss < 4; ++ss)
                *(bf16x8*)(sY + (tid + 512 * ss) * 8) = pack_f4(pfa[ss], pfb[ss]);
        }
        __syncthreads();
        // ---- GEMM: each wave owns one 32-col B group ----
        f32x16 acc[2];
        #pragma unroll
        for (int i = 0; i < 2; ++i)
            #pragma unroll
            for (int r = 0; r < 16; ++r) acc[i][r] = 0.f;
        #pragma unroll 8
        for (int k16 = 0; k16 < 16; ++k16) {
            bf16x8 a0 = *(const bf16x8*)(sY + ((k16 * 2 + 0) * 64 + l) * 8);
            bf16x8 a1 = *(const bf16x8*)(sY + ((k16 * 2 + 1) * 64 + l) * 8);
            bf16x8 b0 = *(const bf16x8*)(Bsw + ((k16 * 8 + w) * 64 + l) * 8);
            acc[0] = mfma32(a0, b0, acc[0]);
            acc[1] = mfma32(a1, b0, acc[1]);
        }
        __syncthreads();             // A reads done; region becomes Y
        {
            const int col = w * 32 + (l & 31);
            #pragma unroll
            for (int rt = 0; rt < 2; ++rt)
                #pragma unroll
                for (int reg = 0; reg < 16; ++reg) {
                    const int row = rt * 32 + (reg & 3) + 8 * (reg >> 2) + 4 * (l >> 5);
                    sY[row * SY + col] = f2bf(acc[rt][reg]);
                }
        }
        __syncthreads();

        // ---- issue abn A-tile prefetch NOW (flies under the lab edge loop) ----
        if (side == 0) {
            const float* Xa = abn_feats + bt * (NROW * NF);
            #pragma unroll
            for (int ss = 0; ss < 4; ++ss) {
                const int s = tid + 512 * ss;
                const int k16 = s >> 7, rt = (s >> 6) & 1, ll = s & 63;
                const float* p = Xa + (rt * 32 + (ll & 31)) * NF
                               + k16 * 16 + ((ll >> 5) & 1) * 8;
                pfa[ss] = *(const float4*)p;
                pfb[ss] = *(const float4*)(p + 4);
            }
        }

        // ---- edge reduction: (edge-half eh, col t); 64 edges each ----
        const int eh = tid >> 8;
        const int t = tid & 255;
        const short* yt = sY + t;
        const float* cbt = cb + t;
        const int ob0 = (__builtin_amdgcn_readfirstlane(sE[63]) >> 16) & 255;
        const int ob1 = (__builtin_amdgcn_readfirstlane(sE[64]) >> 16) & 255;
        const bool bshared = (ob0 == ob1);           // organ run crosses e63/e64
        const int ebase = eh * 64;
        float racc = 0.f;
        int curo = (__builtin_amdgcn_readfirstlane(sE[ebase]) >> 16) & 255;
        for (int i0 = 0; i0 < 64; i0 += 8) {
            int   pk8[8];
            float cb8[8], y8[8];
            #pragma unroll
            for (int j = 0; j < 8; ++j) {
                const int pk = __builtin_amdgcn_readfirstlane(sE[ebase + i0 + j]);
                pk8[j] = pk;
                cb8[j] = cbt[(pk & 0xffff) * NF];
                y8[j]  = bf2f(yt[(pk >> 24) * SY]);
            }
            #pragma unroll
            for (int j = 0; j < 8; ++j) {
                const int o = (pk8[j] >> 16) & 255;
                if (o != curo) {         // wave-uniform branch
                    if (bshared && curo == ob0) sOv[eh * NF + t] = racc;
                    else if (side == 0) sAcc[curo * SLD + t] = racc * sInv[curo];
                    else                sAcc[curo * SLD + t] += racc * sInv[curo];
                    racc = 0.f; curo = o;
                }
                racc += tanh_fast(y8[j] + cb8[j]);
            }
        }
        if (bshared && curo == ob0) sOv[eh * NF + t] = racc;
        else if (side == 0) sAcc[curo * SLD + t] = racc * sInv[curo];
        else                sAcc[curo * SLD + t] += racc * sInv[curo];

        if (bshared) {                   // block-uniform
            __syncthreads();
            if (tid < NF) {
                const float v = sOv[tid] + sOv[NF + tid];
                if (side == 0) sAcc[ob0 * SLD + tid] = v * sInvL[ob0];
                else           sAcc[ob0 * SLD + tid] += v * sInvA[ob0];
            }
        }
    }
    __syncthreads();                     // sAcc complete; sY free for backend

    // ---- backend: organ GEMMs + output add (same block, own data) ----
    float* sSt  = (float*)sY;                    // 16640 B
    float* sMsg = (float*)sY + NORG * SLD;       // 16640 B (total 33280 <= 33792)
    gemm_small8_borg(sAcc, (const short*)(ws + WS_SW_ORG),
                     (const float*)(ws + WS_BORG), sMsk, sSt, tid);
    __syncthreads();
    gemm_small8_vec(sSt, (const short*)(ws + WS_SW_O2A), b_o2a, sMsg, tid);
    __syncthreads();

    // out[a][g] = abn_feats[a][g] + sum_o wcnt[a][o]*msg[o][g]
    {
        const int t = tid & 255, rh = tid >> 8;
        float mr[NORG];
        #pragma unroll
        for (int o = 0; o < NORG; ++o) mr[o] = sMsg[o * SLD + t];
        const float* src = abn_feats + bt * (NROW * NF);
        float* dst = out + bt * (NROW * NF);
        #pragma unroll 8
        for (int a0 = 0; a0 < 32; ++a0) {
            const int a = rh * 32 + a0;
            float s = src[a * NF + t];
            #pragma unroll
            for (int o = 0; o < NORG; ++o) s += sWc[a * NORG + o] * mr[o];
            dst[a * NF + t] = s;
        }
    }
}

// ---------------------------------------------------------------------------
// Fallback path (ws too small): pk_addsum_fb (raw sumRel@D) + kg_main.
// ---------------------------------------------------------------------------
__global__ __launch_bounds__(256) void pk_addsum_fb(const float* __restrict__ D,
                                                    char* __restrict__ ws) {
    __shared__ __align__(16) float sP[4 * 1024];
    const int tid = threadIdx.x;
    const int nb = blockIdx.x;
    const int l = tid & 63, w = tid >> 6;
    const float* sr = (const float*)(ws + WS_SUMREL);
    f32x16 acc;
    #pragma unroll
    for (int r = 0; r < 16; ++r) acc[r] = 0.f;
    const int row = l & 31;
    const int kk = ((l >> 5) & 1) * 8;
    const int n = nb * 32 + (l & 31);
    const float* cp = sr + row * NC;
    #pragma unroll 4
    for (int k16 = 0; k16 < 12; ++k16) {
        const int k = w * 192 + k16 * 16 + kk;
        bf16x8 af;
        if (row < NORG) {
            af = pack_a16(cp + k);
        } else {
            #pragma unroll
            for (int j = 0; j < 8; ++j) af[j] = 0;
        }
        const float* dp = D + k * NF + n;
        bf16x8 bv;
        #pragma unroll
        for (int j = 0; j < 8; ++j) bv[j] = f2bf(dp[j * NF]);
        acc = mfma32(af, bv, acc);
    }
    #pragma unroll
    for (int r = 0; r < 16; ++r) sP[w * 1024 + r * 64 + l] = acc[r];
    __syncthreads();
    float* outp = (float*)(ws + WS_ADDSUM);
    #pragma unroll
    for (int q = 0; q < 4; ++q) {
        const int idx2 = q * 256 + tid;
        float v = sP[idx2] + sP[1024 + idx2] + sP[2048 + idx2] + sP[3072 + idx2];
        const int reg = idx2 >> 6, ll = idx2 & 63;
        const int er = (reg & 3) + 8 * (reg >> 2) + 4 * (ll >> 5);
        const int col = nb * 32 + (ll & 31);
        if (er < NORG) outp[er * NF + col] = v;
    }
}

__device__ __forceinline__ void stage_A(const float* __restrict__ X, short* __restrict__ sA, int tid) {
    #pragma unroll
    for (int ss = 0; ss < 8; ++ss) {
        const int s = tid + 256 * ss;
        const int k16 = s >> 7, rt = (s >> 6) & 1, l = s & 63;
        const int row = rt * 32 + (l & 31);
        const int kb = k16 * 16 + ((l >> 5) & 1) * 8;
        *(bf16x8*)(sA + s * 8) = pack_a16(X + row * NF + kb);
    }
}

template <int POST>   // 0: tanh * mask ; 1: plain
__device__ __forceinline__ void gemm_small(
    const float* __restrict__ sIn, const short* __restrict__ Bsw,
    const float* __restrict__ bias, const float* __restrict__ mask,
    float* __restrict__ sOut, int tid) {
    const int l = tid & 63, w = tid >> 6;
    f32x4 acc[4];
    #pragma unroll
    for (int i = 0; i < 4; ++i) { acc[i][0] = 0.f; acc[i][1] = 0.f; acc[i][2] = 0.f; acc[i][3] = 0.f; }
    #pragma unroll 2
    for (int k32 = 0; k32 < 8; ++k32) {
        const float* ap = sIn + (l & 15) * SLD + k32 * 32 + ((l >> 4) & 3) * 8;
        bf16x8 af = pack_a16(ap);
        #pragma unroll
        for (int nt = 0; nt < 4; ++nt) {
            bf16x8 bfv = *(const bf16x8*)(Bsw + ((k32 * 16 + w * 4 + nt) * 64 + l) * 8);
            acc[nt] = mfma16(af, bfv, acc[nt]);
        }
    }
    #pragma unroll
    for (int nt = 0; nt < 4; ++nt) {
        const int col = w * 64 + nt * 16 + (l & 15);
        const float b = bias[col];
        #pragma unroll
        for (int reg = 0; reg < 4; ++reg) {
            const int row = ((l >> 4) & 3) * 4 + reg;
            float v = acc[nt][reg] + b;
            if (POST == 0) v = tanh_fast(v) * mask[row];
            sOut[row * SLD + col] = v;
        }
    }
}

template <bool LAB>
__device__ __forceinline__ void side_pass(
    const float* __restrict__ X, const short* __restrict__ Bsw,
    const float* __restrict__ cb, const float* __restrict__ addR,
    const float* __restrict__ sInv, const int* __restrict__ sE,
    short* __restrict__ sA, float* __restrict__ sAcc, int tid) {
    __syncthreads();                 // prior users of region done
    stage_A(X, sA, tid);
    __syncthreads();
    const int l = tid & 63, w = tid >> 6;
    f32x16 acc[2][2];
    #pragma unroll
    for (int i = 0; i < 2; ++i)
        #pragma unroll
        for (int j = 0; j < 2; ++j)
            #pragma unroll
            for (int r = 0; r < 16; ++r) acc[i][j][r] = 0.f;
    #pragma unroll 8
    for (int k16 = 0; k16 < 16; ++k16) {
        bf16x8 a0 = *(const bf16x8*)(sA + ((k16 * 2 + 0) * 64 + l) * 8);
        bf16x8 a1 = *(const bf16x8*)(sA + ((k16 * 2 + 1) * 64 + l) * 8);
        bf16x8 b0 = *(const bf16x8*)(Bsw + ((k16 * 8 + 2 * w + 0) * 64 + l) * 8);
        bf16x8 b1 = *(const bf16x8*)(Bsw + ((k16 * 8 + 2 * w + 1) * 64 + l) * 8);
        acc[0][0] = mfma32(a0, b0, acc[0][0]);
        acc[1][0] = mfma32(a1, b0, acc[1][0]);
        acc[0][1] = mfma32(a0, b1, acc[0][1]);
        acc[1][1] = mfma32(a1, b1, acc[1][1]);
    }
    __syncthreads();                 // all sA reads done; region becomes sY
    short* sYs = sA;
    #pragma unroll
    for (int rt = 0; rt < 2; ++rt)
        #pragma unroll
        for (int nt = 0; nt < 2; ++nt) {
            const int col = w * 64 + nt * 32 + (l & 31);
            #pragma unroll
            for (int reg = 0; reg < 16; ++reg) {
                const int row = rt * 32 + (reg & 3) + 8 * (reg >> 2) + 4 * (l >> 5);
                sYs[row * SY + col] = f2bf(acc[rt][nt][reg]);
            }
        }
    __syncthreads();
    const int t = tid;
    if (LAB) {
        #pragma unroll
        for (int o = 0; o < NORG; ++o)
            sAcc[o * SLD + t] = addR[o * NF + t] * sInv[o];
    }
    float racc = 0.f;
    int curo = (sE[0] >> 16) & 255;
    #pragma unroll 4
    for (int i = 0; i < NE; ++i) {
        const int pk = sE[i];
        const int o = (pk >> 16) & 255;
        if (o != curo) {             // wave-uniform branch
            sAcc[curo * SLD + t] += racc * sInv[curo];
            racc = 0.f; curo = o;
        }
        const float yv = bf2f(sYs[(pk >> 24) * SY + t]);
        racc += tanh_fast(yv + cb[(pk & 0xffff) * NF + t]);
    }
    sAcc[curo * SLD + t] += racc * sInv[curo];
}

__global__ __launch_bounds__(256, 2) void kg_main(
    const float* __restrict__ lab_feats, const float* __restrict__ abn_feats,
    const float* __restrict__ b_org, const float* __restrict__ b_o2a,
    const char* __restrict__ ws, float* __restrict__ out) {
    __shared__ __align__(16) short sY[NROW * SY];        // 33792 B; aliases A-frags
    __shared__ __align__(16) float sAcc[NORG * SLD];     // 16640 B; later sMsg
    __shared__ __align__(16) float sSt [NORG * SLD];     // 16640 B
    __shared__ int   sEL[NE], sEA[NE];
    __shared__ float sInvL[NORG], sInvA[NORG], sMsk[NORG];

    const int tid = threadIdx.x;
    const int bt = blockIdx.x;

    if (tid < NE) {
        sEL[tid] = ((const int*)(ws + WS_SRTL))[tid];
        sEA[tid] = ((const int*)(ws + WS_SRTA))[tid];
    } else {
        const int u = tid - NE;
        if      (u < 16) sInvL[u]      = ((const float*)(ws + WS_INVL))[u];
        else if (u < 32) sInvA[u - 16] = ((const float*)(ws + WS_INVA))[u - 16];
        else if (u < 48) sMsk[u - 32]  = ((const float*)(ws + WS_MASK))[u - 32];
    }

    const float* Xl = lab_feats + bt * (NROW * NF);
    const float* Xa = abn_feats + bt * (NROW * NF);
    side_pass<true >(Xl, (const short*)(ws + WS_SW_LAB1),
                     (const float*)(ws + WS_LAB_CB), (const float*)(ws + WS_ADDSUM),
                     sInvL, sEL, sY, sAcc, tid);
    side_pass<false>(Xa, (const short*)(ws + WS_SW_ABN1),
                     (const float*)(ws + WS_ABN_CB), nullptr,
                     sInvA, sEA, sY, sAcc, tid);
    __syncthreads();

    gemm_small<0>(sAcc, (const short*)(ws + WS_SW_ORG), b_org, sMsk, sSt, tid);
    __syncthreads();
    float* sMsg = sAcc;   // alias (input of <1> is sSt)
    gemm_small<1>(sSt, (const short*)(ws + WS_SW_O2A), b_o2a, nullptr, sMsg, tid);
    __syncthreads();

    {
        const int g = tid;
        float mr[NORG];
        #pragma unroll
        for (int o = 0; o < NORG; ++o) mr[o] = sMsg[o * SLD + g];
        const float* src = abn_feats + bt * (NROW * NF);
        float* dst = out + bt * (NROW * NF);
        const float* wc = (const float*)(ws + WS_WCNT);
        #pragma unroll 4
        for (int a = 0; a < NROW; ++a) {
            float s = src[a * NF + g];
            #pragma unroll
            for (int o = 0; o < NORG; ++o) s += wc[a * NORG + o] * mr[o];
            dst[a * NF + g] = s;
        }
    }
}

// ---------------------------------------------------------------------------
extern "C" void kernel_launch(void* const* d_in, const int* in_sizes, int n_in,
                              void* d_out, int out_size, void* d_ws, size_t ws_size,
                              hipStream_t stream) {
    const float* lab_feats   = (const float*)d_in[0];
    const float* abn_feats   = (const float*)d_in[1];
    const float* lab_concept = (const float*)d_in[2];
    const float* abn_concept = (const float*)d_in[3];
    const float* lab_rel     = (const float*)d_in[4];
    const float* abn_rel     = (const float*)d_in[5];
    const float* W_lab       = (const float*)d_in[6];
    const float* b_lab       = (const float*)d_in[7];
    const float* W_abn       = (const float*)d_in[8];
    const float* b_abn       = (const float*)d_in[9];
    const float* W_org       = (const float*)d_in[10];
    const float* b_org       = (const float*)d_in[11];
    const float* D           = (const float*)d_in[12];
    const float* W_o2a       = (const float*)d_in[13];
    const float* b_o2a       = (const float*)d_in[14];
    const int* lab_idx     = (const int*)d_in[16];
    const int* lab_org_idx = (const int*)d_in[17];
    const int* abn_idx     = (const int*)d_in[18];
    const int* abn_org_idx = (const int*)d_in[19];
    const int* o2a_abn_idx = (const int*)d_in[20];
    const int* o2a_org_idx = (const int*)d_in[21];
    char* ws = (char*)d_ws;
    float* out = (float*)d_out;

    if (ws_size >= (size_t)WS_NEED) {
        pk_pre2<<<433, 256, 0, stream>>>(W_lab, W_abn, W_org, W_o2a, D, lab_rel,
                                         lab_concept, abn_concept, abn_rel,
                                         b_lab, b_abn,
                                         lab_idx, lab_org_idx, abn_idx, abn_org_idx,
                                         o2a_abn_idx, o2a_org_idx, ws);
        pk_mid<<<8, 256, 0, stream>>>(b_org, ws);
        kg_fuse2<<<NBT, 512, 0, stream>>>(lab_feats, abn_feats, b_o2a, ws, out);
    } else {
        pk_pre2<<<241, 256, 0, stream>>>(W_lab, W_abn, W_org, W_o2a, D, lab_rel,
                                         lab_concept, abn_concept, abn_rel,
                                         b_lab, b_abn,
                                         lab_idx, lab_org_idx, abn_idx, abn_org_idx,
                                         o2a_abn_idx, o2a_org_idx, ws);
        pk_addsum_fb<<<8, 256, 0, stream>>>(D, ws);
        kg_main<<<NBT, 256, 0, stream>>>(lab_feats, abn_feats, b_org, b_o2a, ws, out);
    }
}

// Round 12
// 195.875 us; speedup vs baseline: 1.0213x; 1.0213x over previous
//
#include <hip/hip_runtime.h>
#include <math.h>

// Problem constants
#define NBT 512
#define NF  256
#define NC  768
#define NROW 64
#define NORG 16
#define NE  128
#define SLD 260      // fp32 LDS row stride (16-row tiles)
#define SY  264      // bf16 LDS row stride for y

// ---- ws byte offsets ----
#define WS_SW_LAB1 0         // 256x256 bf16, 32-style frag order
#define WS_SW_ABN1 131072
#define WS_SW_ORG  1441792   // 256x256, 16-style
#define WS_SW_O2A  1572864
#define WS_SUMREL  1703936   // 16x768 f32 per-organ sums of lab_rel
#define WS_LAB_CB  1753088   // 128x256 f32 (bias folded)
#define WS_ABN_CB  1884160
#define WS_BORG    2015232   // 16x256 f32 borg bias matrix (full path)
#define WS_ADDSUM  2015232   // alias: raw sumRel@D for fallback path
#define WS_WCNT    2031616   // 64x16 f32
#define WS_INVL    2035712
#define WS_INVA    2035776
#define WS_MASK    2035840
#define WS_SRTL    2035904   // 128 ints: (row<<24)|(org<<16)|e, organ-sorted ASC
#define WS_SRTA    2036544
#define WS_DW      2097152   // 768x256 f32 = D @ W_org (full path)
#define WS_NEED    2883584

typedef __attribute__((ext_vector_type(8)))  short bf16x8;
typedef __attribute__((ext_vector_type(16))) float f32x16;
typedef __attribute__((ext_vector_type(4)))  float f32x4;

__device__ __forceinline__ short f2bf(float f) {
    union { float f; unsigned u; } v; v.f = f;
    unsigned r = v.u + 0x7FFF + ((v.u >> 16) & 1);   // RNE
    return (short)(r >> 16);
}
__device__ __forceinline__ float bf2f(short s) {
    return __uint_as_float(((unsigned)(unsigned short)s) << 16);
}
__device__ __forceinline__ float tanh_fast(float x) {
    float xc = fminf(fmaxf(x, -15.f), 15.f);
    float e = __expf(2.f * xc);
    return 1.f - 2.f * __builtin_amdgcn_rcpf(e + 1.f);
}
__device__ __forceinline__ f32x16 mfma32(bf16x8 a, bf16x8 b, f32x16 c) {
    return __builtin_amdgcn_mfma_f32_32x32x16_bf16(a, b, c, 0, 0, 0);
}
__device__ __forceinline__ f32x4 mfma16(bf16x8 a, bf16x8 b, f32x4 c) {
    return __builtin_amdgcn_mfma_f32_16x16x32_bf16(a, b, c, 0, 0, 0);
}
__device__ __forceinline__ bf16x8 pack_f4(float4 x0, float4 x1) {
    union { bf16x8 v; unsigned u[4]; } r;
    r.u[0] = __builtin_amdgcn_perm(__float_as_uint(x0.y), __float_as_uint(x0.x), 0x07060302);
    r.u[1] = __builtin_amdgcn_perm(__float_as_uint(x0.w), __float_as_uint(x0.z), 0x07060302);
    r.u[2] = __builtin_amdgcn_perm(__float_as_uint(x1.y), __float_as_uint(x1.x), 0x07060302);
    r.u[3] = __builtin_amdgcn_perm(__float_as_uint(x1.w), __float_as_uint(x1.z), 0x07060302);
    return r.v;
}
__device__ __forceinline__ bf16x8 pack_a16(const float* __restrict__ p) {
    float4 x0 = *(const float4*)p;
    float4 x1 = *(const float4*)(p + 4);
    return pack_f4(x0, x1);
}

// ---------------------------------------------------------------------------
// pk_pre2: 433 blocks (full path) / 241 (fallback):
//   0..63    cb tables (B read on-the-fly from global W)
//   64..111  sumRel (48 parallel blocks -> WS_SUMREL)
//   112      metadata (counts, sorted edge lists, wcnt)
//   113..240 weight swizzles (LAB1, ABN1, ORG, O2A)
//   241..432 DW = D @ W_org (192 tiny blocks; independent of sumRel)
// ---------------------------------------------------------------------------
__device__ __forceinline__ void swz32(const float* __restrict__ src, short* __restrict__ dst, int s) {
    const int l = s & 63, rest = s >> 6;
    const int nt = rest & 7, k16 = rest >> 3;
    const int n = nt * 32 + (l & 31);
    const int kb = k16 * 16 + ((l >> 5) & 1) * 8;
    bf16x8 v;
    #pragma unroll
    for (int j = 0; j < 8; ++j) v[j] = f2bf(src[(kb + j) * NF + n]);
    *(bf16x8*)(dst + s * 8) = v;
}
__device__ __forceinline__ void swz16(const float* __restrict__ src, short* __restrict__ dst, int s) {
    const int l = s & 63, rest = s >> 6;
    const int nt = rest & 15, k32 = rest >> 4;
    const int n = nt * 16 + (l & 15);
    const int kb = k32 * 32 + ((l >> 4) & 3) * 8;
    bf16x8 v;
    #pragma unroll
    for (int j = 0; j < 8; ++j) v[j] = f2bf(src[(kb + j) * NF + n]);
    *(bf16x8*)(dst + s * 8) = v;
}

__global__ __launch_bounds__(256) void pk_pre2(
    const float* __restrict__ W_lab, const float* __restrict__ W_abn,
    const float* __restrict__ W_org,
    const float* __restrict__ W_o2a, const float* __restrict__ D,
    const float* __restrict__ lab_rel,
    const float* __restrict__ lab_con, const float* __restrict__ abn_con,
    const float* __restrict__ abn_rel,
    const float* __restrict__ b_lab, const float* __restrict__ b_abn,
    const int* __restrict__ lab_idx, const int* __restrict__ lab_org_idx,
    const int* __restrict__ abn_idx, const int* __restrict__ abn_org_idx,
    const int* __restrict__ o2a_abn_idx, const int* __restrict__ o2a_org_idx,
    char* __restrict__ ws) {
    __shared__ __align__(16) float sP[4 * 1024];     // 16 KB cross-wave reduce
    const int bid = blockIdx.x;
    const int tid = threadIdx.x;
    if (bid < 64) {
        // ---- cb tables: (con[idx]+rel) @ W2 + bias.  B read on-the-fly. ----
        const int l = tid & 63, w = tid >> 6;
        const int side = bid >> 5;                   // 0 lab, 1 abn
        const int b2 = bid & 31;
        const int mq = b2 >> 3, nb = b2 & 7;         // 4 m-tiles x 8 n-tiles
        const int em = mq * 32;
        const float* W2  = side ? (W_abn + NF * NF) : (W_lab + NF * NF);
        const float* con = side ? abn_con : lab_con;
        const float* rel = side ? abn_rel : lab_rel;
        const int*   idx = side ? abn_idx : lab_idx;

        f32x16 acc;
        #pragma unroll
        for (int r = 0; r < 16; ++r) acc[r] = 0.f;

        const int e  = em + (l & 31);
        const int kk = ((l >> 5) & 1) * 8;
        const int n  = nb * 32 + (l & 31);
        const float* cp = con + idx[e] * NC;
        const float* rp = rel + e * NC;
        #pragma unroll 4
        for (int k16 = 0; k16 < 12; ++k16) {
            const int k = (w * 12 + k16) * 16 + kk;
            float4 c0 = *(const float4*)(cp + k);
            float4 c1 = *(const float4*)(cp + k + 4);
            float4 r0 = *(const float4*)(rp + k);
            float4 r1 = *(const float4*)(rp + k + 4);
            float v[8] = {c0.x + r0.x, c0.y + r0.y, c0.z + r0.z, c0.w + r0.w,
                          c1.x + r1.x, c1.y + r1.y, c1.z + r1.z, c1.w + r1.w};
            bf16x8 af;
            #pragma unroll
            for (int j = 0; j < 8; ++j) af[j] = f2bf(v[j]);
            const float* wp = W2 + k * NF + n;       // B col n, rows k..k+7
            bf16x8 bv;
            #pragma unroll
            for (int j = 0; j < 8; ++j) bv[j] = f2bf(wp[j * NF]);
            acc = mfma32(af, bv, acc);
        }
        #pragma unroll
        for (int r = 0; r < 16; ++r) sP[w * 1024 + r * 64 + l] = acc[r];
        __syncthreads();
        float* outp = (float*)(ws + (side ? WS_ABN_CB : WS_LAB_CB));
        const float* bias = side ? b_abn : b_lab;
        #pragma unroll
        for (int q = 0; q < 4; ++q) {
            const int idx2 = q * 256 + tid;
            float v = sP[idx2] + sP[1024 + idx2] + sP[2048 + idx2] + sP[3072 + idx2];
            const int reg = idx2 >> 6, ll = idx2 & 63;
            const int er = (reg & 3) + 8 * (reg >> 2) + 4 * (ll >> 5);
            const int col = nb * 32 + (ll & 31);
            outp[(em + er) * NF + col] = v + bias[col];
        }
    } else if (bid < 112) {
        // ---- sumRel[o][k] = sum over lab edges with org==o of lab_rel[e][k] ----
        const int b2 = bid - 64;
        const int o = b2 / 3, kth = b2 % 3;
        const int k = kth * 256 + tid;
        float s = 0.f;
        #pragma unroll 16
        for (int e = 0; e < NE; ++e) {
            const float v = lab_rel[e * NC + k];
            s += (lab_org_idx[e] == o) ? v : 0.f;
        }
        ((float*)(ws + WS_SUMREL))[o * NC + k] = s;
    } else if (bid == 112) {
        // ---- metadata: counts, organ-sorted edge lists, wcnt ----
        __shared__ int cL[NORG], cA[NORG], cC[NROW * NORG];
        __shared__ int goL[NORG + 1], goA[NORG + 1], curL[NORG], curA[NORG];
        const int t = tid;
        for (int i = t; i < NROW * NORG; i += 256) cC[i] = 0;
        if (t < NORG) { cL[t] = 0; cA[t] = 0; }
        __syncthreads();
        if (t < NE) {
            atomicAdd(&cL[lab_org_idx[t]], 1);
            atomicAdd(&cA[abn_org_idx[t]], 1);
            atomicAdd(&cC[o2a_abn_idx[t] * NORG + o2a_org_idx[t]], 1);
        }
        __syncthreads();
        if (t == 0) { int s = 0; for (int o = 0; o < NORG; ++o) { goL[o] = s; s += cL[o]; } goL[NORG] = s; }
        if (t == 1) { int s = 0; for (int o = 0; o < NORG; ++o) { goA[o] = s; s += cA[o]; } goA[NORG] = s; }
        __syncthreads();
        if (t < NORG) { curL[t] = goL[t]; curA[t] = goA[t]; }
        __syncthreads();
        if (t < NE) {
            const int ol = lab_org_idx[t], oa = abn_org_idx[t];
            int p = atomicAdd(&curL[ol], 1);
            ((int*)(ws + WS_SRTL))[p] = (lab_idx[t] << 24) | (ol << 16) | t;
            int q = atomicAdd(&curA[oa], 1);
            ((int*)(ws + WS_SRTA))[q] = (abn_idx[t] << 24) | (oa << 16) | t;
        }
        if (t < NORG) {
            ((float*)(ws + WS_INVL))[t] = cL[t] ? 1.f / (float)cL[t] : 0.f;
            ((float*)(ws + WS_INVA))[t] = cA[t] ? 1.f / (float)cA[t] : 0.f;
            ((float*)(ws + WS_MASK))[t] = (cL[t] || cA[t]) ? 1.f : 0.f;
        }
        if (t < NROW) {
            int dega = 0;
            for (int o = 0; o < NORG; ++o) dega += cC[t * NORG + o];
            float inv = 1.f / (float)(dega > 1 ? dega : 1);
            for (int o = 0; o < NORG; ++o)
                ((float*)(ws + WS_WCNT))[t * NORG + o] = (float)cC[t * NORG + o] * inv;
        }
    } else if (bid < 241) {
        const int gid = (bid - 113) * 256 + tid;
        if      (gid <  8192) swz32(W_lab, (short*)(ws + WS_SW_LAB1), gid);
        else if (gid < 16384) swz32(W_abn, (short*)(ws + WS_SW_ABN1), gid - 8192);
        else if (gid < 24576) swz16(W_org, (short*)(ws + WS_SW_ORG),  gid - 16384);
        else                  swz16(W_o2a, (short*)(ws + WS_SW_O2A),  gid - 24576);
    } else {
        // ---- DW = D @ W_org  (768x256 @ 256x256), 192 blocks of 32x32 ----
        const int b = bid - 241;
        const int mq = b >> 3, nb = b & 7;           // 24 m-tiles x 8 n-tiles
        const int l = tid & 63, w = tid >> 6;
        f32x16 acc;
        #pragma unroll
        for (int r = 0; r < 16; ++r) acc[r] = 0.f;
        const int row = mq * 32 + (l & 31);
        const int kk = ((l >> 5) & 1) * 8;
        const int n = nb * 32 + (l & 31);
        #pragma unroll
        for (int k16 = 0; k16 < 4; ++k16) {
            const int k = w * 64 + k16 * 16 + kk;
            bf16x8 af = pack_a16(D + row * NF + k);
            const float* wp = W_org + k * NF + n;
            bf16x8 bv;
            #pragma unroll
            for (int j = 0; j < 8; ++j) bv[j] = f2bf(wp[j * NF]);
            acc = mfma32(af, bv, acc);
        }
        #pragma unroll
        for (int r = 0; r < 16; ++r) sP[w * 1024 + r * 64 + l] = acc[r];
        __syncthreads();
        float* outp = (float*)(ws + WS_DW);
        #pragma unroll
        for (int q = 0; q < 4; ++q) {
            const int idx2 = q * 256 + tid;
            float v = sP[idx2] + sP[1024 + idx2] + sP[2048 + idx2] + sP[3072 + idx2];
            const int reg = idx2 >> 6, ll = idx2 & 63;
            const int er = (reg & 3) + 8 * (reg >> 2) + 4 * (ll >> 5);
            const int col = nb * 32 + (ll & 31);
            outp[(mq * 32 + er) * NF + col] = v;
        }
    }
}

// ---------------------------------------------------------------------------
// pk_mid: 8 blocks. borg = (invL-rowscaled sumRel) @ DW + b_org -> WS_BORG.
// ---------------------------------------------------------------------------
__global__ __launch_bounds__(256) void pk_mid(
    const float* __restrict__ b_org, char* __restrict__ ws) {
    __shared__ __align__(16) float sP[4 * 1024];
    const int tid = threadIdx.x;
    const int nb = blockIdx.x;
    const int l = tid & 63, w = tid >> 6;
    const float* sr = (const float*)(ws + WS_SUMREL);
    const float* dw = (const float*)(ws + WS_DW);
    const float* invL = (const float*)(ws + WS_INVL);
    f32x16 acc;
    #pragma unroll
    for (int r = 0; r < 16; ++r) acc[r] = 0.f;
    const int row = l & 31;
    const int kk = ((l >> 5) & 1) * 8;
    const int n = nb * 32 + (l & 31);
    const float il = (row < NORG) ? invL[row] : 0.f;
    const float* cp = sr + row * NC;
    #pragma unroll 4
    for (int k16 = 0; k16 < 12; ++k16) {
        const int k = w * 192 + k16 * 16 + kk;
        bf16x8 af;
        if (row < NORG) {
            float4 x0 = *(const float4*)(cp + k);
            float4 x1 = *(const float4*)(cp + k + 4);
            af[0] = f2bf(x0.x * il); af[1] = f2bf(x0.y * il);
            af[2] = f2bf(x0.z * il); af[3] = f2bf(x0.w * il);
            af[4] = f2bf(x1.x * il); af[5] = f2bf(x1.y * il);
            af[6] = f2bf(x1.z * il); af[7] = f2bf(x1.w * il);
        } else {
            #pragma unroll
            for (int j = 0; j < 8; ++j) af[j] = 0;
        }
        const float* dp = dw + k * NF + n;
        bf16x8 bv;
        #pragma unroll
        for (int j = 0; j < 8; ++j) bv[j] = f2bf(dp[j * NF]);
        acc = mfma32(af, bv, acc);
    }
    #pragma unroll
    for (int r = 0; r < 16; ++r) sP[w * 1024 + r * 64 + l] = acc[r];
    __syncthreads();
    float* outp = (float*)(ws + WS_BORG);
    #pragma unroll
    for (int q = 0; q < 4; ++q) {
        const int idx2 = q * 256 + tid;
        float v = sP[idx2] + sP[1024 + idx2] + sP[2048 + idx2] + sP[3072 + idx2];
        const int reg = idx2 >> 6, ll = idx2 & 63;
        const int er = (reg & 3) + 8 * (reg >> 2) + 4 * (ll >> 5);
        const int col = nb * 32 + (ll & 31);
        if (er < NORG) outp[er * NF + col] = v + b_org[col];
    }
}

// ---------------------------------------------------------------------------
// gemm_small8 variants: 512-thread (8-wave). Each wave owns 2 n-tiles of 16.
// ---------------------------------------------------------------------------
__device__ __forceinline__ void gemm_small8_borg(
    const float* __restrict__ sIn, const short* __restrict__ Bsw,
    const float* __restrict__ borg, const float* __restrict__ mask,
    float* __restrict__ sOut, int tid) {
    const int l = tid & 63, w = tid >> 6;            // w 0..7
    f32x4 acc[2];
    #pragma unroll
    for (int i = 0; i < 2; ++i) { acc[i][0] = 0.f; acc[i][1] = 0.f; acc[i][2] = 0.f; acc[i][3] = 0.f; }
    #pragma unroll 2
    for (int k32 = 0; k32 < 8; ++k32) {
        const float* ap = sIn + (l & 15) * SLD + k32 * 32 + ((l >> 4) & 3) * 8;
        bf16x8 af = pack_a16(ap);
        #pragma unroll
        for (int nt = 0; nt < 2; ++nt) {
            bf16x8 bfv = *(const bf16x8*)(Bsw + ((k32 * 16 + w * 2 + nt) * 64 + l) * 8);
            acc[nt] = mfma16(af, bfv, acc[nt]);
        }
    }
    #pragma unroll
    for (int nt = 0; nt < 2; ++nt) {
        const int col = (w * 2 + nt) * 16 + (l & 15);
        #pragma unroll
        for (int reg = 0; reg < 4; ++reg) {
            const int row = ((l >> 4) & 3) * 4 + reg;
            float v = acc[nt][reg] + borg[row * NF + col];
            sOut[row * SLD + col] = tanh_fast(v) * mask[row];
        }
    }
}
__device__ __forceinline__ void gemm_small8_vec(
    const float* __restrict__ sIn, const short* __restrict__ Bsw,
    const float* __restrict__ bias, float* __restrict__ sOut, int tid) {
    const int l = tid & 63, w = tid >> 6;
    f32x4 acc[2];
    #pragma unroll
    for (int i = 0; i < 2; ++i) { acc[i][0] = 0.f; acc[i][1] = 0.f; acc[i][2] = 0.f; acc[i][3] = 0.f; }
    #pragma unroll 2
    for (int k32 = 0; k32 < 8; ++k32) {
        const float* ap = sIn + (l & 15) * SLD + k32 * 32 + ((l >> 4) & 3) * 8;
        bf16x8 af = pack_a16(ap);
        #pragma unroll
        for (int nt = 0; nt < 2; ++nt) {
            bf16x8 bfv = *(const bf16x8*)(Bsw + ((k32 * 16 + w * 2 + nt) * 64 + l) * 8);
            acc[nt] = mfma16(af, bfv, acc[nt]);
        }
    }
    #pragma unroll
    for (int nt = 0; nt < 2; ++nt) {
        const int col = (w * 2 + nt) * 16 + (l & 15);
        const float b = bias[col];
        #pragma unroll
        for (int reg = 0; reg < 4; ++reg) {
            const int row = ((l >> 4) & 3) * 4 + reg;
            sOut[row * SLD + col] = acc[nt][reg] + b;
        }
    }
}

// ---------------------------------------------------------------------------
// kg_fuse2: ONE block per bt (512 blocks x 512 threads). Lab then abn pass
// accumulate organ means into LDS (inv folded at flush; addR folded into the
// borg bias matrix); backend runs in the same block.
// R12: edge loop software double-buffers 8-edge groups (next group's cb/y
// loads fly under current group's tanh chain); first 4 B-fragments per side
// issued before the stage barriers.
// ---------------------------------------------------------------------------
__global__ __launch_bounds__(512, 2) void kg_fuse2(
    const float* __restrict__ lab_feats, const float* __restrict__ abn_feats,
    const float* __restrict__ b_o2a,
    const char* __restrict__ ws, float* __restrict__ out) {
    __shared__ __align__(16) short sY[NROW * SY];    // 33792 B: A-stage / Y / backend
    __shared__ __align__(16) float sAcc[NORG * SLD]; // 16640 B organ means
    __shared__ float sWc[NROW * NORG];               // 4096 B
    __shared__ int sEL[NE], sEA[NE];
    __shared__ float sOv[2 * NF];                    // boundary-organ partials
    __shared__ float sInvL[NORG], sInvA[NORG], sMsk[NORG];

    const int tid = threadIdx.x;
    const int bt = blockIdx.x;

    if (tid < NE)          sEL[tid]      = ((const int*)(ws + WS_SRTL))[tid];
    else if (tid < 2 * NE) sEA[tid - NE] = ((const int*)(ws + WS_SRTA))[tid - NE];
    else {
        const int u = tid - 2 * NE;
        if      (u < 16) sInvL[u]       = ((const float*)(ws + WS_INVL))[u];
        else if (u < 32) sInvA[u - 16]  = ((const float*)(ws + WS_INVA))[u - 16];
        else if (u < 48) sMsk[u - 32]   = ((const float*)(ws + WS_MASK))[u - 32];
    }
    #pragma unroll
    for (int i = tid; i < NROW * NORG; i += 512)
        sWc[i] = ((const float*)(ws + WS_WCNT))[i];
    // zero-init organ means (cols 0..255)
    #pragma unroll
    for (int i = tid; i < NORG * NF; i += 512)
        sAcc[(i >> 8) * SLD + (i & 255)] = 0.f;

    const int l = tid & 63, w = tid >> 6;

    for (int side = 0; side < 2; ++side) {
        const float* X   = (side ? abn_feats : lab_feats) + bt * (NROW * NF);
        const short* Bsw = (const short*)(ws + (side ? WS_SW_ABN1 : WS_SW_LAB1));
        const float* cb  = (const float*)(ws + (side ? WS_ABN_CB : WS_LAB_CB));
        const int* sE    = side ? sEA : sEL;
        const float* sInv = side ? sInvA : sInvL;

        // ---- hoist first 4 B fragments (fly over barriers + staging) ----
        bf16x8 bPre[4];
        #pragma unroll
        for (int kp = 0; kp < 4; ++kp)
            bPre[kp] = *(const bf16x8*)(Bsw + ((kp * 8 + w) * 64 + l) * 8);

        __syncthreads();             // prior uses of sY / sAcc ordering
        // ---- stage full A tile (2048 lane-frags) ----
        #pragma unroll
        for (int ss = 0; ss < 4; ++ss) {
            const int s = tid + 512 * ss;
            const int k16 = s >> 7, rt = (s >> 6) & 1, ll = s & 63;
            const int row = rt * 32 + (ll & 31);
            const int kb = k16 * 16 + ((ll >> 5) & 1) * 8;
            *(bf16x8*)(sY + s * 8) = pack_a16(X + row * NF + kb);
        }
        __syncthreads();
        // ---- GEMM: each wave owns one 32-col B group ----
        f32x16 acc[2];
        #pragma unroll
        for (int i = 0; i < 2; ++i)
            #pragma unroll
            for (int r = 0; r < 16; ++r) acc[i][r] = 0.f;
        #pragma unroll
        for (int k16 = 0; k16 < 16; ++k16) {
            bf16x8 a0 = *(const bf16x8*)(sY + ((k16 * 2 + 0) * 64 + l) * 8);
            bf16x8 a1 = *(const bf16x8*)(sY + ((k16 * 2 + 1) * 64 + l) * 8);
            bf16x8 b0 = (k16 < 4) ? bPre[k16]
                        : *(const bf16x8*)(Bsw + ((k16 * 8 + w) * 64 + l) * 8);
            acc[0] = mfma32(a0, b0, acc[0]);
            acc[1] = mfma32(a1, b0, acc[1]);
        }
        __syncthreads();             // A reads done; region becomes Y
        {
            const int col = w * 32 + (l & 31);
            #pragma unroll
            for (int rt = 0; rt < 2; ++rt)
                #pragma unroll
                for (int reg = 0; reg < 16; ++reg) {
                    const int row = rt * 32 + (reg & 3) + 8 * (reg >> 2) + 4 * (l >> 5);
                    sY[row * SY + col] = f2bf(acc[rt][reg]);
                }
        }
        __syncthreads();

        // ---- edge reduction: (edge-half eh, col t); 64 edges each ----
        // double-buffered 8-edge groups: next group's loads overlap current
        // group's tanh chain.
        const int eh = tid >> 8;
        const int t = tid & 255;
        const short* yt = sY + t;
        const float* cbt = cb + t;
        const int ob0 = (__builtin_amdgcn_readfirstlane(sE[63]) >> 16) & 255;
        const int ob1 = (__builtin_amdgcn_readfirstlane(sE[64]) >> 16) & 255;
        const bool bshared = (ob0 == ob1);           // organ run crosses e63/e64
        const int ebase = eh * 64;
        float racc = 0.f;
        int curo = (__builtin_amdgcn_readfirstlane(sE[ebase]) >> 16) & 255;

        int   pkC[8]; float cbC[8], yC[8];
        #pragma unroll
        for (int j = 0; j < 8; ++j) {
            const int pk = __builtin_amdgcn_readfirstlane(sE[ebase + j]);
            pkC[j] = pk;
            cbC[j] = cbt[(pk & 0xffff) * NF];
            yC[j]  = bf2f(yt[(pk >> 24) * SY]);
        }
        #pragma unroll
        for (int g = 0; g < 8; ++g) {
            int pkN[8]; float cbN[8], yN[8];
            if (g < 7) {
                #pragma unroll
                for (int j = 0; j < 8; ++j) {
                    const int pk = __builtin_amdgcn_readfirstlane(sE[ebase + (g + 1) * 8 + j]);
                    pkN[j] = pk;
                    cbN[j] = cbt[(pk & 0xffff) * NF];
                    yN[j]  = bf2f(yt[(pk >> 24) * SY]);
                }
            }
            #pragma unroll
            for (int j = 0; j < 8; ++j) {
                const int o = (pkC[j] >> 16) & 255;
                if (o != curo) {         // wave-uniform branch
                    if (bshared && curo == ob0) sOv[eh * NF + t] = racc;
                    else if (side == 0) sAcc[curo * SLD + t] = racc * sInv[curo];
                    else                sAcc[curo * SLD + t] += racc * sInv[curo];
                    racc = 0.f; curo = o;
                }
                racc += tanh_fast(yC[j] + cbC[j]);
            }
            if (g < 7) {
                #pragma unroll
                for (int j = 0; j < 8; ++j) { pkC[j] = pkN[j]; cbC[j] = cbN[j]; yC[j] = yN[j]; }
            }
        }
        if (bshared && curo == ob0) sOv[eh * NF + t] = racc;
        else if (side == 0) sAcc[curo * SLD + t] = racc * sInv[curo];
        else                sAcc[curo * SLD + t] += racc * sInv[curo];

        if (bshared) {                   // block-uniform
            __syncthreads();
            if (tid < NF) {
                const float v = sOv[tid] + sOv[NF + tid];
                if (side == 0) sAcc[ob0 * SLD + tid] = v * sInvL[ob0];
                else           sAcc[ob0 * SLD + tid] += v * sInvA[ob0];
            }
        }
    }
    __syncthreads();                     // sAcc complete; sY free for backend

    // ---- backend: organ GEMMs + output add (same block, own data) ----
    float* sSt  = (float*)sY;                    // 16640 B
    float* sMsg = (float*)sY + NORG * SLD;       // 16640 B (total 33280 <= 33792)
    gemm_small8_borg(sAcc, (const short*)(ws + WS_SW_ORG),
                     (const float*)(ws + WS_BORG), sMsk, sSt, tid);
    __syncthreads();
    gemm_small8_vec(sSt, (const short*)(ws + WS_SW_O2A), b_o2a, sMsg, tid);
    __syncthreads();

    // out[a][g] = abn_feats[a][g] + sum_o wcnt[a][o]*msg[o][g]
    {
        const int t = tid & 255, rh = tid >> 8;
        float mr[NORG];
        #pragma unroll
        for (int o = 0; o < NORG; ++o) mr[o] = sMsg[o * SLD + t];
        const float* src = abn_feats + bt * (NROW * NF);
        float* dst = out + bt * (NROW * NF);
        #pragma unroll 8
        for (int a0 = 0; a0 < 32; ++a0) {
            const int a = rh * 32 + a0;
            float s = src[a * NF + t];
            #pragma unroll
            for (int o = 0; o < NORG; ++o) s += sWc[a * NORG + o] * mr[o];
            dst[a * NF + t] = s;
        }
    }
}

// ---------------------------------------------------------------------------
// Fallback path (ws too small): pk_addsum_fb (raw sumRel@D) + kg_main.
// ---------------------------------------------------------------------------
__global__ __launch_bounds__(256) void pk_addsum_fb(const float* __restrict__ D,
                                                    char* __restrict__ ws) {
    __shared__ __align__(16) float sP[4 * 1024];
    const int tid = threadIdx.x;
    const int nb = blockIdx.x;
    const int l = tid & 63, w = tid >> 6;
    const float* sr = (const float*)(ws + WS_SUMREL);
    f32x16 acc;
    #pragma unroll
    for (int r = 0; r < 16; ++r) acc[r] = 0.f;
    const int row = l & 31;
    const int kk = ((l >> 5) & 1) * 8;
    const int n = nb * 32 + (l & 31);
    const float* cp = sr + row * NC;
    #pragma unroll 4
    for (int k16 = 0; k16 < 12; ++k16) {
        const int k = w * 192 + k16 * 16 + kk;
        bf16x8 af;
        if (row < NORG) {
            af = pack_a16(cp + k);
        } else {
            #pragma unroll
            for (int j = 0; j < 8; ++j) af[j] = 0;
        }
        const float* dp = D + k * NF + n;
        bf16x8 bv;
        #pragma unroll
        for (int j = 0; j < 8; ++j) bv[j] = f2bf(dp[j * NF]);
        acc = mfma32(af, bv, acc);
    }
    #pragma unroll
    for (int r = 0; r < 16; ++r) sP[w * 1024 + r * 64 + l] = acc[r];
    __syncthreads();
    float* outp = (float*)(ws + WS_ADDSUM);
    #pragma unroll
    for (int q = 0; q < 4; ++q) {
        const int idx2 = q * 256 + tid;
        float v = sP[idx2] + sP[1024 + idx2] + sP[2048 + idx2] + sP[3072 + idx2];
        const int reg = idx2 >> 6, ll = idx2 & 63;
        const int er = (reg & 3) + 8 * (reg >> 2) + 4 * (ll >> 5);
        const int col = nb * 32 + (ll & 31);
        if (er < NORG) outp[er * NF + col] = v;
    }
}

__device__ __forceinline__ void stage_A(const float* __restrict__ X, short* __restrict__ sA, int tid) {
    #pragma unroll
    for (int ss = 0; ss < 8; ++ss) {
        const int s = tid + 256 * ss;
        const int k16 = s >> 7, rt = (s >> 6) & 1, l = s & 63;
        const int row = rt * 32 + (l & 31);
        const int kb = k16 * 16 + ((l >> 5) & 1) * 8;
        *(bf16x8*)(sA + s * 8) = pack_a16(X + row * NF + kb);
    }
}

template <int POST>   // 0: tanh * mask ; 1: plain
__device__ __forceinline__ void gemm_small(
    const float* __restrict__ sIn, const short* __restrict__ Bsw,
    const float* __restrict__ bias, const float* __restrict__ mask,
    float* __restrict__ sOut, int tid) {
    const int l = tid & 63, w = tid >> 6;
    f32x4 acc[4];
    #pragma unroll
    for (int i = 0; i < 4; ++i) { acc[i][0] = 0.f; acc[i][1] = 0.f; acc[i][2] = 0.f; acc[i][3] = 0.f; }
    #pragma unroll 2
    for (int k32 = 0; k32 < 8; ++k32) {
        const float* ap = sIn + (l & 15) * SLD + k32 * 32 + ((l >> 4) & 3) * 8;
        bf16x8 af = pack_a16(ap);
        #pragma unroll
        for (int nt = 0; nt < 4; ++nt) {
            bf16x8 bfv = *(const bf16x8*)(Bsw + ((k32 * 16 + w * 4 + nt) * 64 + l) * 8);
            acc[nt] = mfma16(af, bfv, acc[nt]);
        }
    }
    #pragma unroll
    for (int nt = 0; nt < 4; ++nt) {
        const int col = w * 64 + nt * 16 + (l & 15);
        const float b = bias[col];
        #pragma unroll
        for (int reg = 0; reg < 4; ++reg) {
            const int row = ((l >> 4) & 3) * 4 + reg;
            float v = acc[nt][reg] + b;
            if (POST == 0) v = tanh_fast(v) * mask[row];
            sOut[row * SLD + col] = v;
        }
    }
}

template <bool LAB>
__device__ __forceinline__ void side_pass(
    const float* __restrict__ X, const short* __restrict__ Bsw,
    const float* __restrict__ cb, const float* __restrict__ addR,
    const float* __restrict__ sInv, const int* __restrict__ sE,
    short* __restrict__ sA, float* __restrict__ sAcc, int tid) {
    __syncthreads();                 // prior users of region done
    stage_A(X, sA, tid);
    __syncthreads();
    const int l = tid & 63, w = tid >> 6;
    f32x16 acc[2][2];
    #pragma unroll
    for (int i = 0; i < 2; ++i)
        #pragma unroll
        for (int j = 0; j < 2; ++j)
            #pragma unroll
            for (int r = 0; r < 16; ++r) acc[i][j][r] = 0.f;
    #pragma unroll 8
    for (int k16 = 0; k16 < 16; ++k16) {
        bf16x8 a0 = *(const bf16x8*)(sA + ((k16 * 2 + 0) * 64 + l) * 8);
        bf16x8 a1 = *(const bf16x8*)(sA + ((k16 * 2 + 1) * 64 + l) * 8);
        bf16x8 b0 = *(const bf16x8*)(Bsw + ((k16 * 8 + 2 * w + 0) * 64 + l) * 8);
        bf16x8 b1 = *(const bf16x8*)(Bsw + ((k16 * 8 + 2 * w + 1) * 64 + l) * 8);
        acc[0][0] = mfma32(a0, b0, acc[0][0]);
        acc[1][0] = mfma32(a1, b0, acc[1][0]);
        acc[0][1] = mfma32(a0, b1, acc[0][1]);
        acc[1][1] = mfma32(a1, b1, acc[1][1]);
    }
    __syncthreads();                 // all sA reads done; region becomes sY
    short* sYs = sA;
    #pragma unroll
    for (int rt = 0; rt < 2; ++rt)
        #pragma unroll
        for (int nt = 0; nt < 2; ++nt) {
            const int col = w * 64 + nt * 32 + (l & 31);
            #pragma unroll
            for (int reg = 0; reg < 16; ++reg) {
                const int row = rt * 32 + (reg & 3) + 8 * (reg >> 2) + 4 * (l >> 5);
                sYs[row * SY + col] = f2bf(acc[rt][nt][reg]);
            }
        }
    __syncthreads();
    const int t = tid;
    if (LAB) {
        #pragma unroll
        for (int o = 0; o < NORG; ++o)
            sAcc[o * SLD + t] = addR[o * NF + t] * sInv[o];
    }
    float racc = 0.f;
    int curo = (sE[0] >> 16) & 255;
    #pragma unroll 4
    for (int i = 0; i < NE; ++i) {
        const int pk = sE[i];
        const int o = (pk >> 16) & 255;
        if (o != curo) {             // wave-uniform branch
            sAcc[curo * SLD + t] += racc * sInv[curo];
            racc = 0.f; curo = o;
        }
        const float yv = bf2f(sYs[(pk >> 24) * SY + t]);
        racc += tanh_fast(yv + cb[(pk & 0xffff) * NF + t]);
    }
    sAcc[curo * SLD + t] += racc * sInv[curo];
}

__global__ __launch_bounds__(256, 2) void kg_main(
    const float* __restrict__ lab_feats, const float* __restrict__ abn_feats,
    const float* __restrict__ b_org, const float* __restrict__ b_o2a,
    const char* __restrict__ ws, float* __restrict__ out) {
    __shared__ __align__(16) short sY[NROW * SY];        // 33792 B; aliases A-frags
    __shared__ __align__(16) float sAcc[NORG * SLD];     // 16640 B; later sMsg
    __shared__ __align__(16) float sSt [NORG * SLD];     // 16640 B
    __shared__ int   sEL[NE], sEA[NE];
    __shared__ float sInvL[NORG], sInvA[NORG], sMsk[NORG];

    const int tid = threadIdx.x;
    const int bt = blockIdx.x;

    if (tid < NE) {
        sEL[tid] = ((const int*)(ws + WS_SRTL))[tid];
        sEA[tid] = ((const int*)(ws + WS_SRTA))[tid];
    } else {
        const int u = tid - NE;
        if      (u < 16) sInvL[u]      = ((const float*)(ws + WS_INVL))[u];
        else if (u < 32) sInvA[u - 16] = ((const float*)(ws + WS_INVA))[u - 16];
        else if (u < 48) sMsk[u - 32]  = ((const float*)(ws + WS_MASK))[u - 32];
    }

    const float* Xl = lab_feats + bt * (NROW * NF);
    const float* Xa = abn_feats + bt * (NROW * NF);
    side_pass<true >(Xl, (const short*)(ws + WS_SW_LAB1),
                     (const float*)(ws + WS_LAB_CB), (const float*)(ws + WS_ADDSUM),
                     sInvL, sEL, sY, sAcc, tid);
    side_pass<false>(Xa, (const short*)(ws + WS_SW_ABN1),
                     (const float*)(ws + WS_ABN_CB), nullptr,
                     sInvA, sEA, sY, sAcc, tid);
    __syncthreads();

    gemm_small<0>(sAcc, (const short*)(ws + WS_SW_ORG), b_org, sMsk, sSt, tid);
    __syncthreads();
    float* sMsg = sAcc;   // alias (input of <1> is sSt)
    gemm_small<1>(sSt, (const short*)(ws + WS_SW_O2A), b_o2a, nullptr, sMsg, tid);
    __syncthreads();

    {
        const int g = tid;
        float mr[NORG];
        #pragma unroll
        for (int o = 0; o < NORG; ++o) mr[o] = sMsg[o * SLD + g];
        const float* src = abn_feats + bt * (NROW * NF);
        float* dst = out + bt * (NROW * NF);
        const float* wc = (const float*)(ws + WS_WCNT);
        #pragma unroll 4
        for (int a = 0; a < NROW; ++a) {
            float s = src[a * NF + g];
            #pragma unroll
            for (int o = 0; o < NORG; ++o) s += wc[a * NORG + o] * mr[o];
            dst[a * NF + g] = s;
        }
    }
}

// ---------------------------------------------------------------------------
extern "C" void kernel_launch(void* const* d_in, const int* in_sizes, int n_in,
                              void* d_out, int out_size, void* d_ws, size_t ws_size,
                              hipStream_t stream) {
    const float* lab_feats   = (const float*)d_in[0];
    const float* abn_feats   = (const float*)d_in[1];
    const float* lab_concept = (const float*)d_in[2];
    const float* abn_concept = (const float*)d_in[3];
    const float* lab_rel     = (const float*)d_in[4];
    const float* abn_rel     = (const float*)d_in[5];
    const float* W_lab       = (const float*)d_in[6];
    const float* b_lab       = (const float*)d_in[7];
    const float* W_abn       = (const float*)d_in[8];
    const float* b_abn       = (const float*)d_in[9];
    const float* W_org       = (const float*)d_in[10];
    const float* b_org       = (const float*)d_in[11];
    const float* D           = (const float*)d_in[12];
    const float* W_o2a       = (const float*)d_in[13];
    const float* b_o2a       = (const float*)d_in[14];
    const int* lab_idx     = (const int*)d_in[16];
    const int* lab_org_idx = (const int*)d_in[17];
    const int* abn_idx     = (const int*)d_in[18];
    const int* abn_org_idx = (const int*)d_in[19];
    const int* o2a_abn_idx = (const int*)d_in[20];
    const int* o2a_org_idx = (const int*)d_in[21];
    char* ws = (char*)d_ws;
    float* out = (float*)d_out;

    if (ws_size >= (size_t)WS_NEED) {
        pk_pre2<<<433, 256, 0, stream>>>(W_lab, W_abn, W_org, W_o2a, D, lab_rel,
                                         lab_concept, abn_concept, abn_rel,
                                         b_lab, b_abn,
                                         lab_idx, lab_org_idx, abn_idx, abn_org_idx,
                                         o2a_abn_idx, o2a_org_idx, ws);
        pk_mid<<<8, 256, 0, stream>>>(b_org, ws);
        kg_fuse2<<<NBT, 512, 0, stream>>>(lab_feats, abn_feats, b_o2a, ws, out);
    } else {
        pk_pre2<<<241, 256, 0, stream>>>(W_lab, W_abn, W_org, W_o2a, D, lab_rel,
                                         lab_concept, abn_concept, abn_rel,
                                         b_lab, b_abn,
                                         lab_idx, lab_org_idx, abn_idx, abn_org_idx,
                                         o2a_abn_idx, o2a_org_idx, ws);
        pk_addsum_fb<<<8, 256, 0, stream>>>(D, ws);
        kg_main<<<NBT, 256, 0, stream>>>(lab_feats, abn_feats, b_org, b_o2a, ws, out);
    }
}